// Round 7
// baseline (208.949 us; speedup 1.0000x reference)
//
#include <hip/hip_runtime.h>

// Observation kernel: B x 7 f32 rows -> B x 7 f32 rows, tiny uniform blocks(3,4).
// R4 (LDS-staged): 77us @ 2.29 TB/s — barrier vmcnt(0) drain per tile.
// R6 (streamed UNR=4, VGPR=40): 71us @ 2.48 TB/s, Occ 51%, VALU 15% — compiler
//   recycled store-source regs into next-iter load dests -> per-iter vmcnt
//   drain (store WAR hazard) -> latency exposed every iteration.
// Control: harness fillBuffer hits 6.6 TB/s (83%) on this chip -> machine is fine.
// This version: UNR=8, ALL 16 loads issued before any compute/store (10KB/wave
// in flight), __launch_bounds__(256,6) so load regs never alias store regs,
// exact grid (one batch per thread, no loop-carried WAR). Stores fire-and-forget.

namespace {
constexpr float kL0  = 0.4f;
constexpr float kL1  = 0.08f;
constexpr float kYLo = 0.0f;
constexpr float kYHi = 2.0f;
constexpr float kFar = 10.0f;
constexpr int COLS = 7;
constexpr int TPB  = 256;
constexpr int UNR  = 8;
}

// 4-byte-aligned vector types: row base is only dword-aligned (7*r floats).
typedef float f4u __attribute__((ext_vector_type(4), aligned(4)));
typedef float f2u __attribute__((ext_vector_type(2), aligned(4)));

template <bool EXACT>
__global__ __launch_bounds__(TPB, 6) void obs_kernel(
    const float* __restrict__ state,
    const float* __restrict__ blocks,
    float* __restrict__ out,
    int nrows)
{
    const int gtid = blockIdx.x * TPB + threadIdx.x;
    const long long NT = (long long)gridDim.x * TPB;

    // Tiny uniform blocks: hoist edges to registers once (scalar loads).
    float bxl[3], bxr[3], byb[3], byt[3];
    #pragma unroll
    for (int i = 0; i < 3; ++i) {
        const float x  = blocks[i * 4 + 0];
        const float y  = blocks[i * 4 + 1];
        const float w2 = 0.5f * blocks[i * 4 + 2];
        const float h2 = 0.5f * blocks[i * 4 + 3];
        bxl[i] = x - w2;
        bxr[i] = x + w2;
        byb[i] = y - h2;
        byt[i] = y + h2;
    }

    for (long long r0 = gtid; r0 < nrows; r0 += NT * UNR) {
        // ---- ALL loads first: 16 independent VMEM ops, ~10KB/wave in flight ----
        f4u   a[UNR];      // cx, cy, vx, vy
        float ph[UNR];     // phi (col 4); cols 5,6 dead in output
        #pragma unroll
        for (int k = 0; k < UNR; ++k) {
            const long long r = r0 + (long long)k * NT;
            if (EXACT || r < nrows) {
                const float* p = state + r * COLS;
                a[k]  = *reinterpret_cast<const f4u*>(p);
                ph[k] = p[4];
            }
        }

        // ---- compute + store per row (stores fire-and-forget) ----
        #pragma unroll
        for (int k = 0; k < UNR; ++k) {
            const long long r = r0 + (long long)k * NT;
            if (!EXACT && r >= nrows) continue;

            const float cx  = a[k][0];
            const float cy  = a[k][1];
            const float vx  = a[k][2];
            const float vy  = a[k][3];
            const float phi = ph[k];

            float sa, ca;
            sincosf(fabsf(phi), &sa, &ca);   // cos(phi) == cos(|phi|)
            const float half_x = ca * (kL0 * 0.5f) + sa * (kL1 * 0.5f);
            const float half_y = sa * (kL0 * 0.5f) + ca * (kL1 * 0.5f);

            float up   = kYHi - cy - half_y;
            float down = cy - kYLo - half_y;
            float d1 = kFar, d2 = kFar;
            const float lo = cx - half_x;
            const float hi = cx + half_x;
            const float ylo_e = cy - half_y;   // capsule bottom edge
            const float yhi_e = cy + half_y;   // capsule top edge

            #pragma unroll
            for (int i = 0; i < 3; ++i) {
                const bool x_in = (bxl[i] <= hi && bxl[i] >= lo) ||
                                  (bxr[i] <= hi && bxr[i] >= lo);
                if (x_in) {
                    up   = byt[i] - cy - half_y;
                    down = cy - byb[i] - half_y;
                }
                const bool passed = hi < bxl[i];
                const float dist  = bxl[i] - cx - half_x;
                const bool y1_out = (ylo_e < byb[i]) || (ylo_e > byt[i]);
                const bool y2_out = (yhi_e > byt[i]) || (yhi_e < byb[i]);
                if (passed && y1_out && d1 == kFar) d1 = dist;  // first match wins
                if (passed && y2_out && d2 == kFar) d2 = dist;
            }

            // Out row: [d1, d2, up, down, v_x, v_y, phi]
            float* o = out + r * COLS;
            f4u o4 = {d1, d2, up, down};
            f2u o2 = {vx, vy};
            *reinterpret_cast<f4u*>(o)     = o4;
            *reinterpret_cast<f2u*>(o + 4) = o2;
            o[6] = phi;
        }
    }
}

extern "C" void kernel_launch(void* const* d_in, const int* in_sizes, int n_in,
                              void* d_out, int out_size, void* d_ws, size_t ws_size,
                              hipStream_t stream) {
    const float* state  = (const float*)d_in[0];
    const float* blocks = (const float*)d_in[1];
    float* out = (float*)d_out;

    const int nrows = in_sizes[0] / COLS;
    const long long per = (long long)TPB * UNR;
    long long want = ((long long)nrows + per - 1) / per;
    const int grid = (int)(want < 1 ? 1 : (want > 8192 ? 8192 : want));

    if ((long long)grid * per == nrows) {
        obs_kernel<true ><<<grid, TPB, 0, stream>>>(state, blocks, out, nrows);
    } else {
        obs_kernel<false><<<grid, TPB, 0, stream>>>(state, blocks, out, nrows);
    }
}